// Round 1
// baseline (313.936 us; speedup 1.0000x reference)
//
#include <hip/hip_runtime.h>
#include <hip/hip_bf16.h>

// Problem: N=32, W=64, H=64, C=256, D_STYLE=256. All fp32 in/out.
// out = leaky0.1( (inputs * softmax_c(colsum*q*s) * softmax_wh(inputs·q*s)) @ Wconv )

#define NBATCH 32
#define PIX 4096          // 64*64
#define CH 256
#define SCALE 0.0625f     // 1/sqrt(256)

typedef __attribute__((ext_vector_type(8))) short short8;
typedef __attribute__((ext_vector_type(4))) short short4v;
typedef __attribute__((ext_vector_type(4))) float floatx4;

__device__ __forceinline__ short f2bf(float x) {
    unsigned u = __builtin_bit_cast(unsigned, x);
    u += 0x7fffu + ((u >> 16) & 1u);   // round-to-nearest-even
    return (short)(u >> 16);
}

// ---------------- K1: q = leaky_relu(style @ w_dense, 0.3); zero colsum ------
__global__ __launch_bounds__(256) void style_kernel(
    const float* __restrict__ style, const float* __restrict__ wd,
    float* __restrict__ q, float* __restrict__ colsum)
{
    __shared__ float s[256];
    const int n = blockIdx.x, t = threadIdx.x;
    s[t] = style[n * 256 + t];
    __syncthreads();
    float acc = 0.f;
#pragma unroll 8
    for (int k = 0; k < 256; ++k) acc += s[k] * wd[k * 256 + t];
    q[n * 256 + t] = acc > 0.f ? acc : 0.3f * acc;
    colsum[n * 256 + t] = 0.f;
}

// ---------------- K1t: wT[co][ci] = bf16(w_conv[ci][co]) ---------------------
__global__ void wt_kernel(const float* __restrict__ wc, short* __restrict__ wT)
{
    __shared__ float tile[32][33];
    const int co0 = blockIdx.x * 32, ci0 = blockIdx.y * 32;
    const int tx = threadIdx.x, ty = threadIdx.y;  // 32 x 8
#pragma unroll
    for (int r = 0; r < 4; ++r)
        tile[ty + r * 8][tx] = wc[(ci0 + ty + r * 8) * 256 + co0 + tx];
    __syncthreads();
#pragma unroll
    for (int r = 0; r < 4; ++r)
        wT[(co0 + ty + r * 8) * 256 + ci0 + tx] = f2bf(tile[tx][ty + r * 8]);
}

// ---------------- K2: colsum[n][c] += sum_p in; pa_logits[n][p] = in·q * s ---
__global__ __launch_bounds__(256) void reduce_kernel(
    const float* __restrict__ inp, const float* __restrict__ q,
    float* __restrict__ colsum, float* __restrict__ pa_logits)
{
    const int n = blockIdx.y;
    const int chunk = blockIdx.x;        // 32 chunks of 128 pixels
    const int lane = threadIdx.x & 63, w = threadIdx.x >> 6;
    const float4 qv = *(const float4*)&q[n * 256 + lane * 4];
    float4 cs = make_float4(0.f, 0.f, 0.f, 0.f);
    const int pbase = chunk * 128 + w * 32;
    const float* base = inp + ((size_t)n * PIX + pbase) * CH;
    for (int j = 0; j < 32; ++j) {
        float4 v = *(const float4*)&base[(size_t)j * CH + lane * 4];
        float d = v.x * qv.x + v.y * qv.y + v.z * qv.z + v.w * qv.w;
        cs.x += v.x; cs.y += v.y; cs.z += v.z; cs.w += v.w;
#pragma unroll
        for (int off = 32; off; off >>= 1) d += __shfl_xor(d, off);
        if (lane == 0) pa_logits[n * PIX + pbase + j] = d * SCALE;
    }
    float* cp = colsum + n * 256 + lane * 4;
    atomicAdd(cp + 0, cs.x);
    atomicAdd(cp + 1, cs.y);
    atomicAdd(cp + 2, cs.z);
    atomicAdd(cp + 3, cs.w);
}

// ---------------- K3: ca = softmax_c(colsum*q*s); pa = softmax_p(pa_logits) --
__global__ __launch_bounds__(256) void softmax_kernel(
    const float* __restrict__ colsum, const float* __restrict__ q,
    const float* __restrict__ pa_logits,
    float* __restrict__ ca, float* __restrict__ pa)
{
    __shared__ float red[256];
    const int n = blockIdx.x, t = threadIdx.x;

    // ---- ca over 256 channels ----
    float lg = colsum[n * 256 + t] * q[n * 256 + t] * SCALE;
    red[t] = lg; __syncthreads();
    for (int s = 128; s > 0; s >>= 1) {
        if (t < s) red[t] = fmaxf(red[t], red[t + s]);
        __syncthreads();
    }
    float m = red[0]; __syncthreads();
    float e = expf(lg - m);
    red[t] = e; __syncthreads();
    for (int s = 128; s > 0; s >>= 1) {
        if (t < s) red[t] += red[t + s];
        __syncthreads();
    }
    ca[n * 256 + t] = e / red[0];
    __syncthreads();

    // ---- pa over 4096 pixels ----
    float lv[16];
    float lmax = -1e30f;
#pragma unroll
    for (int i = 0; i < 16; ++i) {
        lv[i] = pa_logits[n * PIX + t + 256 * i];
        lmax = fmaxf(lmax, lv[i]);
    }
    red[t] = lmax; __syncthreads();
    for (int s = 128; s > 0; s >>= 1) {
        if (t < s) red[t] = fmaxf(red[t], red[t + s]);
        __syncthreads();
    }
    float M = red[0]; __syncthreads();
    float ev[16], lsum = 0.f;
#pragma unroll
    for (int i = 0; i < 16; ++i) { ev[i] = expf(lv[i] - M); lsum += ev[i]; }
    red[t] = lsum; __syncthreads();
    for (int s = 128; s > 0; s >>= 1) {
        if (t < s) red[t] += red[t + s];
        __syncthreads();
    }
    float inv = 1.0f / red[0];
#pragma unroll
    for (int i = 0; i < 16; ++i) pa[n * PIX + t + 256 * i] = ev[i] * inv;
}

// ---------------- K4: y = leaky0.1( (in .* ca) @ wT^T .* pa ) via bf16 MFMA --
// 128x128 tile, BK=64, 4 waves (2x2), each wave 64x64 = 4x4 MFMA 16x16x32.
__global__ __launch_bounds__(256) void conv_mfma(
    const float* __restrict__ inp, const float* __restrict__ ca,
    const float* __restrict__ pa, const short* __restrict__ wT,
    float* __restrict__ out)
{
    __shared__ __attribute__((aligned(16))) short As[128][72];  // [pixel][k], pad 8
    __shared__ __attribute__((aligned(16))) short Bs[128][72];  // [co][k],    pad 8

    const int n   = blockIdx.z;
    const int m0  = blockIdx.y * 128;   // pixel base
    const int co0 = blockIdx.x * 128;   // output-channel base
    const int tid = threadIdx.x;
    const int lane = tid & 63, wid = tid >> 6;
    const int wm = wid & 1, wn = wid >> 1;
    const int l16 = lane & 15, quad = lane >> 4;

    floatx4 acc[4][4] = {};

    const float* Abase = inp + ((size_t)(n * PIX + m0)) * CH;
    const short* Bbase = wT + (size_t)co0 * CH;

    const int akq = tid & 15, arb = tid >> 4;  // A staging: 16 float4 per row
    const int bck = tid & 7,  brb = tid >> 3;  // B staging: 8 x 16B per row

    for (int kb = 0; kb < 4; ++kb) {
        const int k0 = kb * 64;
        if (kb) __syncthreads();
        // stage A: 128 pixels x 64 ch, fp32 -> bf16 with ca scale
        const float4 cav = *(const float4*)&ca[n * 256 + k0 + akq * 4];
#pragma unroll
        for (int i = 0; i < 8; ++i) {
            const int r = arb + 16 * i;
            float4 v = *(const float4*)&Abase[(size_t)r * CH + k0 + akq * 4];
            short4v s;
            s.x = f2bf(v.x * cav.x);
            s.y = f2bf(v.y * cav.y);
            s.z = f2bf(v.z * cav.z);
            s.w = f2bf(v.w * cav.w);
            *(short4v*)&As[r][akq * 4] = s;
        }
        // stage B: 128 co x 64 k bf16 (already transposed)
#pragma unroll
        for (int i = 0; i < 4; ++i) {
            const int r = brb + 32 * i;
            *(uint4*)&Bs[r][bck * 8] = *(const uint4*)&Bbase[(size_t)r * CH + k0 + bck * 8];
        }
        __syncthreads();
#pragma unroll
        for (int kk = 0; kk < 64; kk += 32) {
            short8 af[4], bfr[4];
#pragma unroll
            for (int mt = 0; mt < 4; ++mt)
                af[mt] = *(const short8*)&As[wm * 64 + mt * 16 + l16][kk + quad * 8];
#pragma unroll
            for (int nt = 0; nt < 4; ++nt)
                bfr[nt] = *(const short8*)&Bs[wn * 64 + nt * 16 + l16][kk + quad * 8];
#pragma unroll
            for (int mt = 0; mt < 4; ++mt)
#pragma unroll
                for (int nt = 0; nt < 4; ++nt)
                    acc[mt][nt] = __builtin_amdgcn_mfma_f32_16x16x32_bf16(
                        af[mt], bfr[nt], acc[mt][nt], 0, 0, 0);
        }
    }

    // epilogue: z = acc * pa[pixel]; leaky 0.1; store
#pragma unroll
    for (int mt = 0; mt < 4; ++mt) {
#pragma unroll
        for (int reg = 0; reg < 4; ++reg) {
            const int pix = m0 + wm * 64 + mt * 16 + quad * 4 + reg;
            const float pav = pa[n * PIX + pix];
            float* orow = out + ((size_t)(n * PIX + pix)) * CH + co0 + wn * 64;
#pragma unroll
            for (int nt = 0; nt < 4; ++nt) {
                float z = acc[mt][nt][reg] * pav;
                orow[nt * 16 + l16] = z > 0.f ? z : 0.1f * z;
            }
        }
    }
}

extern "C" void kernel_launch(void* const* d_in, const int* in_sizes, int n_in,
                              void* d_out, int out_size, void* d_ws, size_t ws_size,
                              hipStream_t stream) {
    const float* inputs = (const float*)d_in[0];   // [32,64,64,256]
    const float* style  = (const float*)d_in[1];   // [32,256]
    const float* wdense = (const float*)d_in[2];   // [256,256]
    const float* wconv  = (const float*)d_in[3];   // [1,1,256,256] = [ci][co]
    float* out = (float*)d_out;

    // workspace layout (bytes)
    char* ws = (char*)d_ws;
    float* q         = (float*)(ws + 0);        // 32*256
    float* colsum    = (float*)(ws + 32768);    // 32*256
    float* ca        = (float*)(ws + 65536);    // 32*256
    float* pa_logits = (float*)(ws + 98304);    // 32*4096
    float* pa        = (float*)(ws + 622592);   // 32*4096
    short* wT        = (short*)(ws + 1146880);  // 256*256 bf16

    style_kernel<<<NBATCH, 256, 0, stream>>>(style, wdense, q, colsum);
    wt_kernel<<<dim3(8, 8), dim3(32, 8), 0, stream>>>(wconv, wT);
    reduce_kernel<<<dim3(32, NBATCH), 256, 0, stream>>>(inputs, q, colsum, pa_logits);
    softmax_kernel<<<NBATCH, 256, 0, stream>>>(colsum, q, pa_logits, ca, pa);
    conv_mfma<<<dim3(2, 32, NBATCH), 256, 0, stream>>>(inputs, ca, pa, wT, out);
}